// Round 18
// baseline (326.206 us; speedup 1.0000x reference)
//
#include <hip/hip_runtime.h>

// ---------------------------------------------------------------------------
// AttentionLayer (weight-norm in/out proj + softmax cross-attention)
// N=16, TQ=TS=C=E=1024, fp32 in/out.
//
// R14 (5th submit; rounds 14-17 benches were infra failures — kernel never
// ran on hardware): counted-vmcnt + co-residency combined (untested cell of
// the 2x2: R10 drain0/1blk=325, R12 counted/1blk=336, R13 drain0/2blk=320.6).
// 256x128 tile, 8 waves, BK=32; 3-slot LDS ring (72KB -> 2 blocks/CU);
// prefetch depth 2; mid-loop wait = vmcnt(3) (tile t+2's 3 loads stay in
// flight across the barrier; drains tile t+1). Never vmcnt(0) mid-loop.
// Ledger: STAGE(t+2) writes slot (t+2)%3 == (t-1)%3 whose reads closed at
// iter t-1's barrier; epilogue vmcnt(0) when prefetch window closes.
// Swizzle = proven key (row>>1)&3 both sides (0 conflicts).
//
// Memory plan (ws 68MB):
//   ws:  [0,2) Wi16  [2,4) Wo16  [4,36) VT16  [36,68) KT16 -> ctx16
//   d_out [0,32):  x16 -> at16 -> out(lo half)
//   d_out [32,64): h16 -> out(hi half)
//   d_out [64,128): scores f32 -> attn f32 (softmax in-place, final output)
// Inputs never written.
// ---------------------------------------------------------------------------

typedef _Float16 f16_t;
typedef f16_t f16x8 __attribute__((ext_vector_type(8)));
typedef f16_t f16x4 __attribute__((ext_vector_type(4)));
typedef float f32x4 __attribute__((ext_vector_type(4)));

constexpr int BM = 256, BN = 128, BK = 32;
#define SQRT_HALF 0.7071067811865476f

__device__ __forceinline__ void stage16(const f16_t* g, void* lds) {
  __builtin_amdgcn_global_load_lds(
      (const __attribute__((address_space(1))) unsigned int*)g,
      (__attribute__((address_space(3))) unsigned int*)lds, 16, 0, 0);
}

// --------------------------- weight norm (dim=0) ---------------------------
__global__ __launch_bounds__(256) void wnorm_f16_kernel(
    const float* __restrict__ v, const float* __restrict__ g,
    f16_t* __restrict__ o, int C)
{
  int row = blockIdx.x;
  const float* vr = v + (long)row * C;
  float ss = 0.f;
  for (int c = threadIdx.x; c < C; c += 256) { float x = vr[c]; ss += x * x; }
#pragma unroll
  for (int m = 1; m < 64; m <<= 1) ss += __shfl_xor(ss, m, 64);
  __shared__ float red[4];
  if ((threadIdx.x & 63) == 0) red[threadIdx.x >> 6] = ss;
  __syncthreads();
  float tot = red[0] + red[1] + red[2] + red[3];
  float scale = g[row] / sqrtf(tot);
  for (int c = threadIdx.x; c < C; c += 256)
    o[(long)row * C + c] = (f16_t)(vr[c] * scale);
}

// ------------------------- f32 -> f16 convert ------------------------------
__global__ __launch_bounds__(256) void cvt_f16_kernel(
    const float* __restrict__ in, f16_t* __restrict__ o, long n4)
{
  long i = (long)blockIdx.x * 256 + threadIdx.x;
  long stride = (long)gridDim.x * 256;
  for (; i < n4; i += stride) {
    float4 v = reinterpret_cast<const float4*>(in)[i];
    f16x4 c;
    c[0] = (f16_t)v.x; c[1] = (f16_t)v.y; c[2] = (f16_t)v.z; c[3] = (f16_t)v.w;
    *reinterpret_cast<f16x4*>(&o[i * 4]) = c;
  }
}

// ------------------ transpose f32 -> f16: [z][R][C] -> [z][C][R] -----------
__global__ __launch_bounds__(256) void transpose_f16_kernel(
    const float* __restrict__ in, f16_t* __restrict__ o, int R, int C)
{
  __shared__ float t[32][33];
  long zb = (long)blockIdx.z * R * C;
  int r0 = blockIdx.y * 32, c0 = blockIdx.x * 32;
  int tx = threadIdx.x & 31, ty = threadIdx.x >> 5;
#pragma unroll
  for (int i = 0; i < 4; ++i)
    t[ty + i * 8][tx] = in[zb + (long)(r0 + ty + i * 8) * C + c0 + tx];
  __syncthreads();
#pragma unroll
  for (int i = 0; i < 4; ++i) {
    int oc = ty + i * 8;
    o[zb + (long)(c0 + oc) * R + r0 + tx] = (f16_t)t[tx][oc];
  }
}

// --------------------------- GEMM 256x128 (fp16) ---------------------------
// C[M][Nn] = A[M][K] * Bt[Nn][K]^T. 512 threads, 8 waves (4 row x 2 col),
// per-wave output 64x64 (4mf x 4nf of 16x16x32 MFMA). BK=32.
// LDS: 3-slot ring x (A 16KB + B 8KB) = 72KB -> 2 blocks/CU.
// Staging via global_load_lds (A 2 + B 1 chunks/thread); source-swizzled
// slot = chunk ^ ((row>>1)&3); fragment reads XOR same key (conflict-free).
// Loop: STAGE(t+2) -> COMPUTE(t) -> vmcnt(3) -> s_barrier.
// EPI 0: h   = (acc + bias[col] + addt[gi]) * scale -> f16 outH
// EPI 1: scores = acc                               -> f32 outF (batched)
// EPI 2: ctx = acc * scale                          -> f16 outH (batched)
// EPI 3: out = (acc + bias[col] + addt[gi]) * scale -> f32 outF
template <int EPI>
__global__ __launch_bounds__(512) void gemm_f16_kernel(
    const f16_t* __restrict__ A, const f16_t* __restrict__ B,
    int K, long sAb, long sBb,
    const float* __restrict__ bias, const float* __restrict__ addt,
    float scale, float* __restrict__ outF, f16_t* __restrict__ outH,
    long sOb, int Nn)
{
  const int n = blockIdx.z;
  A += (long)n * sAb;
  B += (long)n * sBb;
  const long ob = (long)n * sOb;

  const int row0 = blockIdx.x * BM, col0 = blockIdx.y * BN;
  const int tid = threadIdx.x;
  const int l = tid & 63;
  const int w = tid >> 6;
  const int wr = w >> 1, wc = w & 1;          // 4x2 wave grid
  const int lr = l & 15, lq = l >> 4;

  __shared__ __align__(16) f16_t Ash[3 * BM * BK];   // 48KB (3 slots x 16KB)
  __shared__ __align__(16) f16_t Bsh[3 * BN * BK];   // 24KB (3 slots x 8KB)

  // staging: chunk c -> (row, slot) = (c>>2, c&3); src col = slot^((row>>1)&3).
  // A: 1024 chunks -> threads t and t+512 (rows 0..127, 128..255; key same).
  // B: 512 chunks -> thread t.
  const int srow = tid >> 2;                              // 0..127
  const int scol = 8 * ((tid & 3) ^ ((srow >> 1) & 3));   // swizzled src col
  const int wbase = (tid * 16) & ~1023;                   // wave-uniform base
  const long abase = (long)(row0 + srow) * K + scol;
  const long bbase = (long)(col0 + srow) * K + scol;
  const long rowstep = 128L * (long)K;                    // +128 rows (key same)

  const int fkey = (lr >> 1) & 3;                         // fragment read key
  const int fcol = (lq ^ fkey) * 8;

  f32x4 acc[4][4] = {};

  auto STAGE = [&](int slot, int k0) {
    char* ab = (char*)Ash + slot * 16384;
    char* bb = (char*)Bsh + slot * 8192;
    stage16(A + abase + k0, ab + wbase);
    stage16(A + abase + rowstep + k0, ab + 8192 + wbase);
    stage16(B + bbase + k0, bb + wbase);
  };

  auto COMPUTE = [&](int slot) {
    const int heA = slot * BM * BK;
    const int heB = slot * BN * BK;
    f16x8 af[4], bf[4];
#pragma unroll
    for (int mf = 0; mf < 4; ++mf)
      af[mf] = *reinterpret_cast<const f16x8*>(
          &Ash[heA + (wr * 64 + mf * 16 + lr) * BK + fcol]);
#pragma unroll
    for (int nf = 0; nf < 4; ++nf)
      bf[nf] = *reinterpret_cast<const f16x8*>(
          &Bsh[heB + (wc * 64 + nf * 16 + lr) * BK + fcol]);
    __builtin_amdgcn_s_setprio(1);
#pragma unroll
    for (int mf = 0; mf < 4; ++mf)
#pragma unroll
      for (int nf = 0; nf < 4; ++nf)
        acc[mf][nf] = __builtin_amdgcn_mfma_f32_16x16x32_f16(
            af[mf], bf[nf], acc[mf][nf], 0, 0, 0);
    __builtin_amdgcn_s_setprio(0);
  };

  const int nt = K / BK;
  // prologue: stage tiles 0,1; wait for tile 0 (tile 1's 3 loads may fly).
  STAGE(0, 0);
  if (nt > 1) STAGE(1, BK);
  if (nt > 1) asm volatile("s_waitcnt vmcnt(3)" ::: "memory");
  else        asm volatile("s_waitcnt vmcnt(0)" ::: "memory");
  __builtin_amdgcn_s_barrier();
  asm volatile("" ::: "memory");

  for (int t = 0; t < nt; ++t) {
    if (t + 2 < nt) STAGE((t + 2) % 3, (t + 2) * BK);
    COMPUTE(t % 3);
    if (t + 1 < nt) {
      if (t + 2 < nt) asm volatile("s_waitcnt vmcnt(3)" ::: "memory");
      else            asm volatile("s_waitcnt vmcnt(0)" ::: "memory");
      __builtin_amdgcn_s_barrier();
      asm volatile("" ::: "memory");
    }
  }

#pragma unroll
  for (int mf = 0; mf < 4; ++mf)
#pragma unroll
    for (int nf = 0; nf < 4; ++nf)
#pragma unroll
      for (int r = 0; r < 4; ++r) {
        int row = row0 + wr * 64 + mf * 16 + lq * 4 + r;  // C/D: row=(l>>4)*4+r
        int col = col0 + wc * 64 + nf * 16 + lr;          //      col=l&15
        long gi = (long)row * Nn + col;
        float v = acc[mf][nf][r];
        if constexpr (EPI == 0) {
          outH[gi] = (f16_t)((v + bias[col] + addt[gi]) * scale);
        } else if constexpr (EPI == 1) {
          outF[ob + gi] = v;
        } else if constexpr (EPI == 2) {
          outH[ob + gi] = (f16_t)(v * scale);
        } else {
          outF[gi] = (v + bias[col] + addt[gi]) * scale;
        }
      }
}

// ------- softmax (rows of 1024): in-place f32 + f16 copy -------------------
__global__ __launch_bounds__(256) void softmax_kernel(
    float* __restrict__ sc, f16_t* __restrict__ ah)
{
  long row = blockIdx.x;
  float* p = sc + row * 1024;
  int t = threadIdx.x;
  float4 v = reinterpret_cast<float4*>(p)[t];
  float m = fmaxf(fmaxf(v.x, v.y), fmaxf(v.z, v.w));
#pragma unroll
  for (int mask = 1; mask < 64; mask <<= 1) m = fmaxf(m, __shfl_xor(m, mask, 64));
  __shared__ float red[4], red2[4];
  if ((t & 63) == 0) red[t >> 6] = m;
  __syncthreads();
  m = fmaxf(fmaxf(red[0], red[1]), fmaxf(red[2], red[3]));
  float e0 = expf(v.x - m), e1 = expf(v.y - m);
  float e2 = expf(v.z - m), e3 = expf(v.w - m);
  float s = e0 + e1 + e2 + e3;
#pragma unroll
  for (int mask = 1; mask < 64; mask <<= 1) s += __shfl_xor(s, mask, 64);
  if ((t & 63) == 0) red2[t >> 6] = s;
  __syncthreads();
  s = red2[0] + red2[1] + red2[2] + red2[3];
  float inv = 1.f / s;
  float a0 = e0 * inv, a1 = e1 * inv, a2 = e2 * inv, a3 = e3 * inv;
  reinterpret_cast<float4*>(p)[t] = make_float4(a0, a1, a2, a3);
  f16x4 hv;
  hv[0] = (f16_t)a0; hv[1] = (f16_t)a1; hv[2] = (f16_t)a2; hv[3] = (f16_t)a3;
  *reinterpret_cast<f16x4*>(&ah[row * 1024 + (long)t * 4]) = hv;
}

// ---------------------------------------------------------------------------
extern "C" void kernel_launch(void* const* d_in, const int* in_sizes, int n_in,
                              void* d_out, int out_size, void* d_ws, size_t ws_size,
                              hipStream_t stream)
{
  (void)in_sizes; (void)n_in; (void)out_size; (void)ws_size;
  const float* x   = (const float*)d_in[0];
  const float* te  = (const float*)d_in[1];
  const float* ek  = (const float*)d_in[2];
  const float* ev  = (const float*)d_in[3];
  const float* ipv = (const float*)d_in[4];
  const float* ipg = (const float*)d_in[5];
  const float* ipb = (const float*)d_in[6];
  const float* opv = (const float*)d_in[7];
  const float* opg = (const float*)d_in[8];
  const float* opb = (const float*)d_in[9];

  const long M1 = 1024L * 1024L;
  float* out   = (float*)d_out;                       // [16,1024,1024] final out
  float* attnF = out + 16 * M1;                       // [16,1024,1024] final attn

  // ws (68MB total)
  char* ws = (char*)d_ws;
  f16_t* Wi16  = (f16_t*)(ws);                        // [0,2)
  f16_t* Wo16  = (f16_t*)(ws + (2L << 20));           // [2,4)
  f16_t* VT16  = (f16_t*)(ws + (4L << 20));           // [4,36)
  f16_t* KT16  = (f16_t*)(ws + (36L << 20));          // [36,68)
  f16_t* ctx16 = KT16;                                // reuse (KT dead after GEMM2)

  // d_out scratch
  f16_t* x16  = (f16_t*)d_out;                        // [0,32MB)
  f16_t* h16  = x16 + 16 * M1;                        // [32,64MB)
  float* scores = attnF;                              // [64,128MB), in-place softmax
  f16_t* at16 = (f16_t*)d_out;                        // [0,32MB), after x16 dead

  // 1. weight norm -> f16
  wnorm_f16_kernel<<<dim3(1024), dim3(256), 0, stream>>>(ipv, ipg, Wi16, 1024);
  wnorm_f16_kernel<<<dim3(1024), dim3(256), 0, stream>>>(opv, opg, Wo16, 1024);
  // 2. transposes: KT[n][s][e] = ek[n][e][s]; VT[n][e][s] = ev[n][s][e]
  transpose_f16_kernel<<<dim3(32, 32, 16), dim3(256), 0, stream>>>(ek, KT16, 1024, 1024);
  transpose_f16_kernel<<<dim3(32, 32, 16), dim3(256), 0, stream>>>(ev, VT16, 1024, 1024);
  // 3. x -> f16 (d_out[0,32))
  cvt_f16_kernel<<<dim3(2048), dim3(256), 0, stream>>>(x, x16, 16 * M1 / 4);
  // 4. GEMM1: h = (x16 @ Wi^T + b + te) * sqrt(.5) -> f16 d_out[32,64)
  gemm_f16_kernel<0><<<dim3(64, 8, 1), dim3(512), 0, stream>>>(
      x16, Wi16, 1024, 0L, 0L, ipb, te, SQRT_HALF, nullptr, h16, 0L, 1024);
  // 5. GEMM2: scores = h @ K -> f32 d_out[64,128)
  gemm_f16_kernel<1><<<dim3(4, 8, 16), dim3(512), 0, stream>>>(
      h16, KT16, 1024, M1, M1, nullptr, nullptr, 1.0f, scores, nullptr, M1, 1024);
  // 6. softmax in-place -> attn f32 (final) + at16 f16 (d_out[0,32), x16 dead)
  softmax_kernel<<<dim3(16384), dim3(256), 0, stream>>>(scores, at16);
  // 7. GEMM3: ctx = (at16 @ V) * 32 -> f16 ws (KT dead)
  gemm_f16_kernel<2><<<dim3(4, 8, 16), dim3(512), 0, stream>>>(
      at16, VT16, 1024, M1, M1, nullptr, nullptr, 32.0f, nullptr, ctx16, M1, 1024);
  // 8. GEMM4: out = (ctx16 @ Wo^T + b + x) * sqrt(.5) -> f32 d_out[0,64)
  gemm_f16_kernel<3><<<dim3(64, 8, 1), dim3(512), 0, stream>>>(
      ctx16, Wo16, 1024, 0L, 0L, opb, x, SQRT_HALF, out, nullptr, 0L, 1024);
}

// Round 19
// 317.605 us; speedup vs baseline: 1.0271x; 1.0271x over previous
//
#include <hip/hip_runtime.h>

// ---------------------------------------------------------------------------
// AttentionLayer (weight-norm in/out proj + softmax cross-attention)
// N=16, TQ=TS=C=E=1024, fp32 in/out.
//
// R18: best-proven GEMM (R13: 256x128 tile, 8 waves, BK=32, dbuf 48KB LDS ->
// 2 blocks/CU, drain-0 2-phase STAGE(next)->COMPUTE(cur)->vmcnt(0)->barrier;
// counted-vmcnt reverted — R14 proved it neutral) + aux-launch merges:
// one wnorm kernel for both weights, one transpose kernel for both ek/ev
// (9 -> 7 graph nodes).
//
// Memory plan (ws 68MB):
//   ws:  [0,2) Wi16  [2,4) Wo16  [4,36) VT16  [36,68) KT16 -> ctx16
//   d_out [0,32):  x16 -> at16 -> out(lo half)
//   d_out [32,64): h16 -> out(hi half)
//   d_out [64,128): scores f32 -> attn f32 (softmax in-place, final output)
// Inputs never written.
// ---------------------------------------------------------------------------

typedef _Float16 f16_t;
typedef f16_t f16x8 __attribute__((ext_vector_type(8)));
typedef f16_t f16x4 __attribute__((ext_vector_type(4)));
typedef float f32x4 __attribute__((ext_vector_type(4)));

constexpr int BM = 256, BN = 128, BK = 32;
#define SQRT_HALF 0.7071067811865476f

__device__ __forceinline__ void stage16(const f16_t* g, void* lds) {
  __builtin_amdgcn_global_load_lds(
      (const __attribute__((address_space(1))) unsigned int*)g,
      (__attribute__((address_space(3))) unsigned int*)lds, 16, 0, 0);
}

// ---------------- weight norm (dim=0), both matrices in one launch ---------
__global__ __launch_bounds__(256) void wnorm_both_kernel(
    const float* __restrict__ v1, const float* __restrict__ g1,
    f16_t* __restrict__ o1,
    const float* __restrict__ v2, const float* __restrict__ g2,
    f16_t* __restrict__ o2, int C)
{
  int row = blockIdx.x;
  const float* vr;
  f16_t* o;
  float gv;
  if (row < 1024) { vr = v1 + (long)row * C;          o = o1 + (long)row * C;          gv = g1[row]; }
  else            { vr = v2 + (long)(row - 1024) * C; o = o2 + (long)(row - 1024) * C; gv = g2[row - 1024]; }
  float ss = 0.f;
  for (int c = threadIdx.x; c < C; c += 256) { float x = vr[c]; ss += x * x; }
#pragma unroll
  for (int m = 1; m < 64; m <<= 1) ss += __shfl_xor(ss, m, 64);
  __shared__ float red[4];
  if ((threadIdx.x & 63) == 0) red[threadIdx.x >> 6] = ss;
  __syncthreads();
  float tot = red[0] + red[1] + red[2] + red[3];
  float scale = gv / sqrtf(tot);
  for (int c = threadIdx.x; c < C; c += 256)
    o[c] = (f16_t)(vr[c] * scale);
}

// ------------------------- f32 -> f16 convert ------------------------------
__global__ __launch_bounds__(256) void cvt_f16_kernel(
    const float* __restrict__ in, f16_t* __restrict__ o, long n4)
{
  long i = (long)blockIdx.x * 256 + threadIdx.x;
  long stride = (long)gridDim.x * 256;
  for (; i < n4; i += stride) {
    float4 v = reinterpret_cast<const float4*>(in)[i];
    f16x4 c;
    c[0] = (f16_t)v.x; c[1] = (f16_t)v.y; c[2] = (f16_t)v.z; c[3] = (f16_t)v.w;
    *reinterpret_cast<f16x4*>(&o[i * 4]) = c;
  }
}

// ------ transpose f32 -> f16 for BOTH ek->KT and ev->VT in one launch ------
// z < 16: in1 batch z -> o1;  z >= 16: in2 batch z-16 -> o2.  [z][R][C]->[z][C][R]
__global__ __launch_bounds__(256) void transpose_both_kernel(
    const float* __restrict__ in1, f16_t* __restrict__ o1,
    const float* __restrict__ in2, f16_t* __restrict__ o2, int R, int C)
{
  __shared__ float t[32][33];
  int z = blockIdx.z;
  const float* in;
  f16_t* o;
  long zb;
  if (z < 16) { in = in1; o = o1; zb = (long)z * R * C; }
  else        { in = in2; o = o2; zb = (long)(z - 16) * R * C; }
  int r0 = blockIdx.y * 32, c0 = blockIdx.x * 32;
  int tx = threadIdx.x & 31, ty = threadIdx.x >> 5;
#pragma unroll
  for (int i = 0; i < 4; ++i)
    t[ty + i * 8][tx] = in[zb + (long)(r0 + ty + i * 8) * C + c0 + tx];
  __syncthreads();
#pragma unroll
  for (int i = 0; i < 4; ++i) {
    int oc = ty + i * 8;
    o[zb + (long)(c0 + oc) * R + r0 + tx] = (f16_t)t[tx][oc];
  }
}

// --------------------------- GEMM 256x128 (fp16) ---------------------------
// C[M][Nn] = A[M][K] * Bt[Nn][K]^T. 512 threads, 8 waves (4 row x 2 col),
// per-wave output 64x64 (4mf x 4nf of 16x16x32 MFMA). BK=32.
// LDS: dbuf x (A 16KB + B 8KB) = 48KB -> 2 blocks/CU.
// Staging via global_load_lds (A 2 + B 1 chunks/thread); source-swizzled
// slot = chunk ^ ((row>>1)&3); fragment reads XOR same key (conflict-free).
// Loop: STAGE(next) -> COMPUTE(cur) -> vmcnt(0) -> s_barrier (R13-proven).
// EPI 0: h   = (acc + bias[col] + addt[gi]) * scale -> f16 outH
// EPI 1: scores = acc                               -> f32 outF (batched)
// EPI 2: ctx = acc * scale                          -> f16 outH (batched)
// EPI 3: out = (acc + bias[col] + addt[gi]) * scale -> f32 outF
template <int EPI>
__global__ __launch_bounds__(512) void gemm_f16_kernel(
    const f16_t* __restrict__ A, const f16_t* __restrict__ B,
    int K, long sAb, long sBb,
    const float* __restrict__ bias, const float* __restrict__ addt,
    float scale, float* __restrict__ outF, f16_t* __restrict__ outH,
    long sOb, int Nn)
{
  const int n = blockIdx.z;
  A += (long)n * sAb;
  B += (long)n * sBb;
  const long ob = (long)n * sOb;

  const int row0 = blockIdx.x * BM, col0 = blockIdx.y * BN;
  const int tid = threadIdx.x;
  const int l = tid & 63;
  const int w = tid >> 6;
  const int wr = w >> 1, wc = w & 1;          // 4x2 wave grid
  const int lr = l & 15, lq = l >> 4;

  __shared__ __align__(16) f16_t Ash[2 * BM * BK];   // 32KB
  __shared__ __align__(16) f16_t Bsh[2 * BN * BK];   // 16KB

  // staging: chunk c -> (row, slot) = (c>>2, c&3); src col = slot^((row>>1)&3).
  // A: 1024 chunks -> threads t and t+512 (rows 0..127, 128..255; key same).
  // B: 512 chunks -> thread t.
  const int srow = tid >> 2;                              // 0..127
  const int scol = 8 * ((tid & 3) ^ ((srow >> 1) & 3));   // swizzled src col
  const int wbase = (tid * 16) & ~1023;                   // wave-uniform base
  const long abase = (long)(row0 + srow) * K + scol;
  const long bbase = (long)(col0 + srow) * K + scol;
  const long rowstep = 128L * (long)K;                    // +128 rows (key same)

  const int fkey = (lr >> 1) & 3;                         // fragment read key
  const int fcol = (lq ^ fkey) * 8;

  f32x4 acc[4][4] = {};

  auto STAGE = [&](int half, int k0) {
    stage16(A + abase + k0, (char*)Ash + half * 16384 + wbase);
    stage16(A + abase + rowstep + k0, (char*)Ash + half * 16384 + 8192 + wbase);
    stage16(B + bbase + k0, (char*)Bsh + half * 8192 + wbase);
  };

  auto COMPUTE = [&](int half) {
    const int heA = half * BM * BK;
    const int heB = half * BN * BK;
    f16x8 af[4], bf[4];
#pragma unroll
    for (int mf = 0; mf < 4; ++mf)
      af[mf] = *reinterpret_cast<const f16x8*>(
          &Ash[heA + (wr * 64 + mf * 16 + lr) * BK + fcol]);
#pragma unroll
    for (int nf = 0; nf < 4; ++nf)
      bf[nf] = *reinterpret_cast<const f16x8*>(
          &Bsh[heB + (wc * 64 + nf * 16 + lr) * BK + fcol]);
    __builtin_amdgcn_s_setprio(1);
#pragma unroll
    for (int mf = 0; mf < 4; ++mf)
#pragma unroll
      for (int nf = 0; nf < 4; ++nf)
        acc[mf][nf] = __builtin_amdgcn_mfma_f32_16x16x32_f16(
            af[mf], bf[nf], acc[mf][nf], 0, 0, 0);
    __builtin_amdgcn_s_setprio(0);
  };

  // prologue: stage tile 0, drain, publish
  STAGE(0, 0);
  asm volatile("s_waitcnt vmcnt(0)" ::: "memory");
  __builtin_amdgcn_s_barrier();
  asm volatile("" ::: "memory");

  int cur = 0;
  const int nt = K / BK;
  for (int t = 0; t < nt - 1; ++t) {
    STAGE(cur ^ 1, (t + 1) * BK);   // issue next-tile loads first
    COMPUTE(cur);
    asm volatile("s_waitcnt vmcnt(0)" ::: "memory");
    __builtin_amdgcn_s_barrier();
    asm volatile("" ::: "memory");
    cur ^= 1;
  }
  COMPUTE(cur);

#pragma unroll
  for (int mf = 0; mf < 4; ++mf)
#pragma unroll
    for (int nf = 0; nf < 4; ++nf)
#pragma unroll
      for (int r = 0; r < 4; ++r) {
        int row = row0 + wr * 64 + mf * 16 + lq * 4 + r;  // C/D: row=(l>>4)*4+r
        int col = col0 + wc * 64 + nf * 16 + lr;          //      col=l&15
        long gi = (long)row * Nn + col;
        float v = acc[mf][nf][r];
        if constexpr (EPI == 0) {
          outH[gi] = (f16_t)((v + bias[col] + addt[gi]) * scale);
        } else if constexpr (EPI == 1) {
          outF[ob + gi] = v;
        } else if constexpr (EPI == 2) {
          outH[ob + gi] = (f16_t)(v * scale);
        } else {
          outF[gi] = (v + bias[col] + addt[gi]) * scale;
        }
      }
}

// ------- softmax (rows of 1024): in-place f32 + f16 copy -------------------
__global__ __launch_bounds__(256) void softmax_kernel(
    float* __restrict__ sc, f16_t* __restrict__ ah)
{
  long row = blockIdx.x;
  float* p = sc + row * 1024;
  int t = threadIdx.x;
  float4 v = reinterpret_cast<float4*>(p)[t];
  float m = fmaxf(fmaxf(v.x, v.y), fmaxf(v.z, v.w));
#pragma unroll
  for (int mask = 1; mask < 64; mask <<= 1) m = fmaxf(m, __shfl_xor(m, mask, 64));
  __shared__ float red[4], red2[4];
  if ((t & 63) == 0) red[t >> 6] = m;
  __syncthreads();
  m = fmaxf(fmaxf(red[0], red[1]), fmaxf(red[2], red[3]));
  float e0 = expf(v.x - m), e1 = expf(v.y - m);
  float e2 = expf(v.z - m), e3 = expf(v.w - m);
  float s = e0 + e1 + e2 + e3;
#pragma unroll
  for (int mask = 1; mask < 64; mask <<= 1) s += __shfl_xor(s, mask, 64);
  if ((t & 63) == 0) red2[t >> 6] = s;
  __syncthreads();
  s = red2[0] + red2[1] + red2[2] + red2[3];
  float inv = 1.f / s;
  float a0 = e0 * inv, a1 = e1 * inv, a2 = e2 * inv, a3 = e3 * inv;
  reinterpret_cast<float4*>(p)[t] = make_float4(a0, a1, a2, a3);
  f16x4 hv;
  hv[0] = (f16_t)a0; hv[1] = (f16_t)a1; hv[2] = (f16_t)a2; hv[3] = (f16_t)a3;
  *reinterpret_cast<f16x4*>(&ah[row * 1024 + (long)t * 4]) = hv;
}

// ---------------------------------------------------------------------------
extern "C" void kernel_launch(void* const* d_in, const int* in_sizes, int n_in,
                              void* d_out, int out_size, void* d_ws, size_t ws_size,
                              hipStream_t stream)
{
  (void)in_sizes; (void)n_in; (void)out_size; (void)ws_size;
  const float* x   = (const float*)d_in[0];
  const float* te  = (const float*)d_in[1];
  const float* ek  = (const float*)d_in[2];
  const float* ev  = (const float*)d_in[3];
  const float* ipv = (const float*)d_in[4];
  const float* ipg = (const float*)d_in[5];
  const float* ipb = (const float*)d_in[6];
  const float* opv = (const float*)d_in[7];
  const float* opg = (const float*)d_in[8];
  const float* opb = (const float*)d_in[9];

  const long M1 = 1024L * 1024L;
  float* out   = (float*)d_out;                       // [16,1024,1024] final out
  float* attnF = out + 16 * M1;                       // [16,1024,1024] final attn

  // ws (68MB total)
  char* ws = (char*)d_ws;
  f16_t* Wi16  = (f16_t*)(ws);                        // [0,2)
  f16_t* Wo16  = (f16_t*)(ws + (2L << 20));           // [2,4)
  f16_t* VT16  = (f16_t*)(ws + (4L << 20));           // [4,36)
  f16_t* KT16  = (f16_t*)(ws + (36L << 20));          // [36,68)
  f16_t* ctx16 = KT16;                                // reuse (KT dead after GEMM2)

  // d_out scratch
  f16_t* x16  = (f16_t*)d_out;                        // [0,32MB)
  f16_t* h16  = x16 + 16 * M1;                        // [32,64MB)
  float* scores = attnF;                              // [64,128MB), in-place softmax
  f16_t* at16 = (f16_t*)d_out;                        // [0,32MB), after x16 dead

  // 1. weight norm (both) -> f16
  wnorm_both_kernel<<<dim3(2048), dim3(256), 0, stream>>>(
      ipv, ipg, Wi16, opv, opg, Wo16, 1024);
  // 2. transposes (both): KT[n][s][e] = ek[n][e][s]; VT[n][e][s] = ev[n][s][e]
  transpose_both_kernel<<<dim3(32, 32, 32), dim3(256), 0, stream>>>(
      ek, KT16, ev, VT16, 1024, 1024);
  // 3. x -> f16 (d_out[0,32))
  cvt_f16_kernel<<<dim3(2048), dim3(256), 0, stream>>>(x, x16, 16 * M1 / 4);
  // 4. GEMM1: h = (x16 @ Wi^T + b + te) * sqrt(.5) -> f16 d_out[32,64)
  gemm_f16_kernel<0><<<dim3(64, 8, 1), dim3(512), 0, stream>>>(
      x16, Wi16, 1024, 0L, 0L, ipb, te, SQRT_HALF, nullptr, h16, 0L, 1024);
  // 5. GEMM2: scores = h @ K -> f32 d_out[64,128)
  gemm_f16_kernel<1><<<dim3(4, 8, 16), dim3(512), 0, stream>>>(
      h16, KT16, 1024, M1, M1, nullptr, nullptr, 1.0f, scores, nullptr, M1, 1024);
  // 6. softmax in-place -> attn f32 (final) + at16 f16 (d_out[0,32), x16 dead)
  softmax_kernel<<<dim3(16384), dim3(256), 0, stream>>>(scores, at16);
  // 7. GEMM3: ctx = (at16 @ V) * 32 -> f16 ws (KT dead)
  gemm_f16_kernel<2><<<dim3(4, 8, 16), dim3(512), 0, stream>>>(
      at16, VT16, 1024, M1, M1, nullptr, nullptr, 32.0f, nullptr, ctx16, M1, 1024);
  // 8. GEMM4: out = (ctx16 @ Wo^T + b + x) * sqrt(.5) -> f32 d_out[0,64)
  gemm_f16_kernel<3><<<dim3(64, 8, 1), dim3(512), 0, stream>>>(
      ctx16, Wo16, 1024, 0L, 0L, opb, x, SQRT_HALF, out, nullptr, 0L, 1024);
}

// Round 20
// 313.329 us; speedup vs baseline: 1.0411x; 1.0136x over previous
//
#include <hip/hip_runtime.h>

// ---------------------------------------------------------------------------
// AttentionLayer (weight-norm in/out proj + softmax cross-attention)
// N=16, TQ=TS=C=E=1024, fp32 in/out.
//
// R19: f32-A direct staging. GEMM1 (A=x) and GEMM3 (A=attn) stage their f32
// A-operand straight into LDS via global_load_lds (f32 row = 128B = 8 chunks,
// R9-proven 8-slot swizzle key row&7, 0 conflicts) and convert to f16 at
// fragment-read time ((f16_t) scalar casts = RNE, bit-identical to the old
// cvt kernel). Kills the cvt_f16 launch and softmax's at16 write.
// GEMM core = R13/R18 proven drain-0 2-phase (256x128, 8 waves, BK=32,
// 2 blocks/CU; AF32 LDS = 80KB still 2 blocks/CU).
//
// Memory plan (ws 68MB):
//   ws:  [0,2) Wi16  [2,4) Wo16  [4,36) VT16  [36,68) KT16 -> ctx16
//   d_out [0,64):  out f32 (GEMM4, final)
//   d_out [32,64): h16 (GEMM1 out, dead after GEMM2, inside [0,64) overwrite)
//   d_out [64,128): scores f32 -> attn f32 (softmax in-place, final output)
// Inputs never written.
// ---------------------------------------------------------------------------

typedef _Float16 f16_t;
typedef f16_t f16x8 __attribute__((ext_vector_type(8)));
typedef f16_t f16x4 __attribute__((ext_vector_type(4)));
typedef float f32x4 __attribute__((ext_vector_type(4)));

constexpr int BM = 256, BN = 128, BK = 32;
#define SQRT_HALF 0.7071067811865476f

__device__ __forceinline__ void stage16(const void* g, void* lds) {
  __builtin_amdgcn_global_load_lds(
      (const __attribute__((address_space(1))) unsigned int*)g,
      (__attribute__((address_space(3))) unsigned int*)lds, 16, 0, 0);
}

// ---------------- weight norm (dim=0), both matrices in one launch ---------
__global__ __launch_bounds__(256) void wnorm_both_kernel(
    const float* __restrict__ v1, const float* __restrict__ g1,
    f16_t* __restrict__ o1,
    const float* __restrict__ v2, const float* __restrict__ g2,
    f16_t* __restrict__ o2, int C)
{
  int row = blockIdx.x;
  const float* vr;
  f16_t* o;
  float gv;
  if (row < 1024) { vr = v1 + (long)row * C;          o = o1 + (long)row * C;          gv = g1[row]; }
  else            { vr = v2 + (long)(row - 1024) * C; o = o2 + (long)(row - 1024) * C; gv = g2[row - 1024]; }
  float ss = 0.f;
  for (int c = threadIdx.x; c < C; c += 256) { float x = vr[c]; ss += x * x; }
#pragma unroll
  for (int m = 1; m < 64; m <<= 1) ss += __shfl_xor(ss, m, 64);
  __shared__ float red[4];
  if ((threadIdx.x & 63) == 0) red[threadIdx.x >> 6] = ss;
  __syncthreads();
  float tot = red[0] + red[1] + red[2] + red[3];
  float scale = gv / sqrtf(tot);
  for (int c = threadIdx.x; c < C; c += 256)
    o[c] = (f16_t)(vr[c] * scale);
}

// ------ transpose f32 -> f16 for BOTH ek->KT and ev->VT in one launch ------
__global__ __launch_bounds__(256) void transpose_both_kernel(
    const float* __restrict__ in1, f16_t* __restrict__ o1,
    const float* __restrict__ in2, f16_t* __restrict__ o2, int R, int C)
{
  __shared__ float t[32][33];
  int z = blockIdx.z;
  const float* in;
  f16_t* o;
  long zb;
  if (z < 16) { in = in1; o = o1; zb = (long)z * R * C; }
  else        { in = in2; o = o2; zb = (long)(z - 16) * R * C; }
  int r0 = blockIdx.y * 32, c0 = blockIdx.x * 32;
  int tx = threadIdx.x & 31, ty = threadIdx.x >> 5;
#pragma unroll
  for (int i = 0; i < 4; ++i)
    t[ty + i * 8][tx] = in[zb + (long)(r0 + ty + i * 8) * C + c0 + tx];
  __syncthreads();
#pragma unroll
  for (int i = 0; i < 4; ++i) {
    int oc = ty + i * 8;
    o[zb + (long)(c0 + oc) * R + r0 + tx] = (f16_t)t[tx][oc];
  }
}

// --------------------------- GEMM 256x128 ----------------------------------
// C[M][Nn] = A[M][K] * Bt[Nn][K]^T. 512 threads, 8 waves (4 row x 2 col),
// per-wave output 64x64 (4mf x 4nf of 16x16x32 MFMA). BK=32. Drain-0 2-phase
// loop (R13/R18-proven): STAGE(next) -> COMPUTE(cur) -> vmcnt(0) -> barrier.
//
// A operand: AF32=false -> f16 [M][K]; tile row 64B = 4 chunks, swizzle
//   slot = chunk ^ ((row>>1)&3) (proven 0-conflict). 16KB/buffer.
// AF32=true -> f32 [M][K]; tile row 128B = 8 chunks, swizzle slot =
//   chunk ^ (row&7) (R9-proven 0-conflict geometry). 32KB/buffer; fragments
//   read as 2x f32x4 and cvt to f16 in-register (RNE, bit-identical to a
//   separate cvt pass).
// B operand: always f16, 8KB/buffer, 4-chunk swizzle.
// EPI 0: h   = (acc + bias[col] + addt[gi]) * scale -> f16 outH
// EPI 1: scores = acc                               -> f32 outF (batched)
// EPI 2: ctx = acc * scale                          -> f16 outH (batched)
// EPI 3: out = (acc + bias[col] + addt[gi]) * scale -> f32 outF
template <int EPI, bool AF32>
__global__ __launch_bounds__(512) void gemm_f16_kernel(
    const void* __restrict__ Ap, const f16_t* __restrict__ B,
    int K, long sAb, long sBb,
    const float* __restrict__ bias, const float* __restrict__ addt,
    float scale, float* __restrict__ outF, f16_t* __restrict__ outH,
    long sOb, int Nn)
{
  const int n = blockIdx.z;
  B += (long)n * sBb;
  const long ob = (long)n * sOb;

  const int row0 = blockIdx.x * BM, col0 = blockIdx.y * BN;
  const int tid = threadIdx.x;
  const int l = tid & 63;
  const int w = tid >> 6;
  const int wr = w >> 1, wc = w & 1;          // 4x2 wave grid
  const int lr = l & 15, lq = l >> 4;

  constexpr int ABYTES = (AF32 ? 4 : 2) * BM * BK;   // per half-buffer
  __shared__ __align__(16) char AshRaw[2 * ABYTES];  // 64KB or 32KB
  __shared__ __align__(16) f16_t Bsh[2 * BN * BK];   // 16KB

  // ---- B staging geometry (f16, 4 chunks/row, key (row>>1)&3) ----
  const int srowB = tid >> 2;                             // 0..127
  const int scolB = 8 * ((tid & 3) ^ ((srowB >> 1) & 3)); // f16 elems
  const int wbase = (tid * 16) & ~1023;                   // wave-uniform base
  const long bbase = (long)(col0 + srowB) * K + scolB;

  // ---- A staging geometry ----
  const f16_t* A16 = nullptr;
  const float* A32 = nullptr;
  long abase = 0;
  if constexpr (AF32) {
    A32 = (const float*)Ap + (long)n * sAb;
    const int srowA = tid >> 3;                           // 0..63
    const int scolA = 4 * ((tid & 7) ^ (srowA & 7));      // f32 elems
    abase = (long)(row0 + srowA) * K + scolA;
  } else {
    A16 = (const f16_t*)Ap + (long)n * sAb;
    abase = (long)(row0 + srowB) * K + scolB;
  }

  // fragment read keys
  const int fkeyB = (lr >> 1) & 3;
  const int fcolB = (lq ^ fkeyB) * 8;
  const int fkeyA8 = lr & 7;                              // AF32 8-slot key

  f32x4 acc[4][4] = {};

  auto STAGE = [&](int half, int k0) {
    char* ab = AshRaw + half * ABYTES;
    char* bb = (char*)Bsh + half * 8192;
    if constexpr (AF32) {
      const long rowstepA = 64L * (long)K;
#pragma unroll
      for (int p = 0; p < 4; ++p)
        stage16(A32 + abase + p * rowstepA + k0, ab + p * 8192 + wbase);
    } else {
      const long rowstepA = 128L * (long)K;
      stage16(A16 + abase + k0, ab + wbase);
      stage16(A16 + abase + rowstepA + k0, ab + 8192 + wbase);
    }
    stage16(B + bbase + k0, bb + wbase);
  };

  auto COMPUTE = [&](int half) {
    const char* ab = AshRaw + half * ABYTES;
    const int heB = half * BN * BK;
    f16x8 af[4], bf[4];
#pragma unroll
    for (int mf = 0; mf < 4; ++mf) {
      const int ar = wr * 64 + mf * 16 + lr;
      if constexpr (AF32) {
        f32x4 a0 = *reinterpret_cast<const f32x4*>(
            ab + ar * 128 + (((2 * lq) ^ fkeyA8) * 16));
        f32x4 a1 = *reinterpret_cast<const f32x4*>(
            ab + ar * 128 + (((2 * lq + 1) ^ fkeyA8) * 16));
        f16x8 v;
        v[0] = (f16_t)a0[0]; v[1] = (f16_t)a0[1];
        v[2] = (f16_t)a0[2]; v[3] = (f16_t)a0[3];
        v[4] = (f16_t)a1[0]; v[5] = (f16_t)a1[1];
        v[6] = (f16_t)a1[2]; v[7] = (f16_t)a1[3];
        af[mf] = v;
      } else {
        const int fcolA = (lq ^ ((lr >> 1) & 3)) * 8;
        af[mf] = *reinterpret_cast<const f16x8*>(ab + (ar * BK + fcolA) * 2);
      }
    }
#pragma unroll
    for (int nf = 0; nf < 4; ++nf)
      bf[nf] = *reinterpret_cast<const f16x8*>(
          &Bsh[heB + (wc * 64 + nf * 16 + lr) * BK + fcolB]);
    __builtin_amdgcn_s_setprio(1);
#pragma unroll
    for (int mf = 0; mf < 4; ++mf)
#pragma unroll
      for (int nf = 0; nf < 4; ++nf)
        acc[mf][nf] = __builtin_amdgcn_mfma_f32_16x16x32_f16(
            af[mf], bf[nf], acc[mf][nf], 0, 0, 0);
    __builtin_amdgcn_s_setprio(0);
  };

  // prologue: stage tile 0, drain, publish
  STAGE(0, 0);
  asm volatile("s_waitcnt vmcnt(0)" ::: "memory");
  __builtin_amdgcn_s_barrier();
  asm volatile("" ::: "memory");

  int cur = 0;
  const int nt = K / BK;
  for (int t = 0; t < nt - 1; ++t) {
    STAGE(cur ^ 1, (t + 1) * BK);   // issue next-tile loads first
    COMPUTE(cur);
    asm volatile("s_waitcnt vmcnt(0)" ::: "memory");
    __builtin_amdgcn_s_barrier();
    asm volatile("" ::: "memory");
    cur ^= 1;
  }
  COMPUTE(cur);

#pragma unroll
  for (int mf = 0; mf < 4; ++mf)
#pragma unroll
    for (int nf = 0; nf < 4; ++nf)
#pragma unroll
      for (int r = 0; r < 4; ++r) {
        int row = row0 + wr * 64 + mf * 16 + lq * 4 + r;  // C/D: row=(l>>4)*4+r
        int col = col0 + wc * 64 + nf * 16 + lr;          //      col=l&15
        long gi = (long)row * Nn + col;
        float v = acc[mf][nf][r];
        if constexpr (EPI == 0) {
          outH[gi] = (f16_t)((v + bias[col] + addt[gi]) * scale);
        } else if constexpr (EPI == 1) {
          outF[ob + gi] = v;
        } else if constexpr (EPI == 2) {
          outH[ob + gi] = (f16_t)(v * scale);
        } else {
          outF[gi] = (v + bias[col] + addt[gi]) * scale;
        }
      }
}

// ------- softmax (rows of 1024): in-place f32 -------------------------------
__global__ __launch_bounds__(256) void softmax_kernel(float* __restrict__ sc)
{
  long row = blockIdx.x;
  float* p = sc + row * 1024;
  int t = threadIdx.x;
  float4 v = reinterpret_cast<float4*>(p)[t];
  float m = fmaxf(fmaxf(v.x, v.y), fmaxf(v.z, v.w));
#pragma unroll
  for (int mask = 1; mask < 64; mask <<= 1) m = fmaxf(m, __shfl_xor(m, mask, 64));
  __shared__ float red[4], red2[4];
  if ((t & 63) == 0) red[t >> 6] = m;
  __syncthreads();
  m = fmaxf(fmaxf(red[0], red[1]), fmaxf(red[2], red[3]));
  float e0 = expf(v.x - m), e1 = expf(v.y - m);
  float e2 = expf(v.z - m), e3 = expf(v.w - m);
  float s = e0 + e1 + e2 + e3;
#pragma unroll
  for (int mask = 1; mask < 64; mask <<= 1) s += __shfl_xor(s, mask, 64);
  if ((t & 63) == 0) red2[t >> 6] = s;
  __syncthreads();
  s = red2[0] + red2[1] + red2[2] + red2[3];
  float inv = 1.f / s;
  reinterpret_cast<float4*>(p)[t] =
      make_float4(e0 * inv, e1 * inv, e2 * inv, e3 * inv);
}

// ---------------------------------------------------------------------------
extern "C" void kernel_launch(void* const* d_in, const int* in_sizes, int n_in,
                              void* d_out, int out_size, void* d_ws, size_t ws_size,
                              hipStream_t stream)
{
  (void)in_sizes; (void)n_in; (void)out_size; (void)ws_size;
  const float* x   = (const float*)d_in[0];
  const float* te  = (const float*)d_in[1];
  const float* ek  = (const float*)d_in[2];
  const float* ev  = (const float*)d_in[3];
  const float* ipv = (const float*)d_in[4];
  const float* ipg = (const float*)d_in[5];
  const float* ipb = (const float*)d_in[6];
  const float* opv = (const float*)d_in[7];
  const float* opg = (const float*)d_in[8];
  const float* opb = (const float*)d_in[9];

  const long M1 = 1024L * 1024L;
  float* out   = (float*)d_out;                       // [16,1024,1024] final out
  float* attnF = out + 16 * M1;                       // [16,1024,1024] final attn

  // ws (68MB total)
  char* ws = (char*)d_ws;
  f16_t* Wi16  = (f16_t*)(ws);                        // [0,2)
  f16_t* Wo16  = (f16_t*)(ws + (2L << 20));           // [2,4)
  f16_t* VT16  = (f16_t*)(ws + (4L << 20));           // [4,36)
  f16_t* KT16  = (f16_t*)(ws + (36L << 20));          // [36,68)
  f16_t* ctx16 = KT16;                                // reuse (KT dead after GEMM2)

  // d_out scratch
  f16_t* h16 = (f16_t*)d_out + 16 * M1;               // [32,64MB), dead after GEMM2
  float* scores = attnF;                              // [64,128MB), in-place softmax

  // 1. weight norm (both) -> f16
  wnorm_both_kernel<<<dim3(2048), dim3(256), 0, stream>>>(
      ipv, ipg, Wi16, opv, opg, Wo16, 1024);
  // 2. transposes (both): KT[n][s][e] = ek[n][e][s]; VT[n][e][s] = ev[n][s][e]
  transpose_both_kernel<<<dim3(32, 32, 32), dim3(256), 0, stream>>>(
      ek, KT16, ev, VT16, 1024, 1024);
  // 3. GEMM1: h = (x @ Wi^T + b + te) * sqrt(.5) -> f16 d_out[32,64) (A=x f32)
  gemm_f16_kernel<0, true><<<dim3(64, 8, 1), dim3(512), 0, stream>>>(
      x, Wi16, 1024, 0L, 0L, ipb, te, SQRT_HALF, nullptr, h16, 0L, 1024);
  // 4. GEMM2: scores = h @ K -> f32 d_out[64,128)
  gemm_f16_kernel<1, false><<<dim3(4, 8, 16), dim3(512), 0, stream>>>(
      h16, KT16, 1024, M1, M1, nullptr, nullptr, 1.0f, scores, nullptr, M1, 1024);
  // 5. softmax in-place -> attn f32 (final output)
  softmax_kernel<<<dim3(16384), dim3(256), 0, stream>>>(scores);
  // 6. GEMM3: ctx = (attn @ V) * 32 -> f16 ws (A = attn f32; KT dead)
  gemm_f16_kernel<2, true><<<dim3(4, 8, 16), dim3(512), 0, stream>>>(
      attnF, VT16, 1024, M1, M1, nullptr, nullptr, 32.0f, nullptr, ctx16, M1, 1024);
  // 7. GEMM4: out = (ctx16 @ Wo^T + b + x) * sqrt(.5) -> f32 d_out[0,64)
  gemm_f16_kernel<3, false><<<dim3(64, 8, 1), dim3(512), 0, stream>>>(
      ctx16, Wo16, 1024, 0L, 0L, opb, x, SQRT_HALF, out, nullptr, 0L, 1024);
}